// Round 10
// baseline (881.320 us; speedup 1.0000x reference)
//
#include <hip/hip_runtime.h>
#include <hip/hip_bf16.h>

// Problem: T=512, B=64, N=256, H=64, D=128, P=64.
// Stage 1: x2n = input(32768x128) @ W2n^T(128x256) + b2n          (gemm_xwT)
// Stage 2: 16384 independent LSTM cells scanned over 512 steps    (lstm_scan)
// Stage 3: out = ON(32768x256) @ Wout^T(256x64) + bout            (gemm_xwT)
// Workspace: x2n 32MB + ON 32MB = 64MB of d_ws.
//
// Scan (round-10): R7 numerics (ext-slice MFMA init, K=32 MFMA, merged-rcp
// NL, packed cvt, deferred g-reduction) + two diagnosed fixes:
//   - Weight fragments pinned INSIDE the t-loop ("+v" each iteration):
//     R6/R9 showed pin-before-loop lets the compiler rematerialize weights
//     from global every step (VGPR_Count 136 vs 128-reg weight set) — the
//     hidden reload traffic is the persistent ~600cyc/step stall candidate.
//     In-loop pins make the values loop-carried-modified -> must stay live.
//   - Per-q ordering (12 MFMAs then that q's NL): q+1's MFMAs are
//     independent of q's NL, so the MFMA pipe drains under trans/VALU work
//     (separate pipes) instead of serializing as one 840-cyc block.
//   - x prefetched 2 steps ahead (HBM ~900cyc < one step, margin 2x).

typedef __attribute__((ext_vector_type(4))) float f32x4;
typedef __attribute__((ext_vector_type(4))) short s16x4;
typedef __attribute__((ext_vector_type(8))) short s16x8;
typedef __attribute__((ext_vector_type(4))) unsigned u32x4;

__device__ inline short bf16r(float f) {            // round-to-nearest-even bf16
    unsigned u = __builtin_bit_cast(unsigned, f);
    u += 0x7fffu + ((u >> 16) & 1u);
    return (short)(u >> 16);
}
__device__ inline float bf2f(short s) {
    unsigned u = ((unsigned)(unsigned short)s) << 16;
    return __builtin_bit_cast(float, u);
}
__device__ inline unsigned pkbf(float a, float b) { // (bf16(a) | bf16(b)<<16), RNE
    unsigned r;
    asm("v_cvt_pk_bf16_f32 %0, %1, %2" : "=v"(r) : "v"(a), "v"(b));
    return r;
}
__device__ inline f32x4 mfma32(s16x8 a, s16x8 b, f32x4 c) {
    return __builtin_amdgcn_mfma_f32_16x16x32_bf16(a, b, c, 0, 0, 0);
}

// ---------------------------------------------------------------------------
// Generic fp32 GEMM: Out(MxN) = X(MxK) @ Wt(NxK)^T + bias(N).  M%64==0,
// N%64==0, K%32==0.  grid = (M/64, N/64), block = 256.
// ---------------------------------------------------------------------------
__global__ __launch_bounds__(256) void gemm_xwT(
    const float* __restrict__ X, const float* __restrict__ Wt,
    const float* __restrict__ bias, float* __restrict__ Out,
    int N, int K)
{
    __shared__ float Xs[32][68];
    __shared__ float Ws[32][68];
    const int tid = threadIdx.x;
    const int tx = tid & 15, ty = tid >> 4;
    const int m0 = blockIdx.x * 64, n0 = blockIdx.y * 64;
    const int kq = tid & 7, mr = tid >> 3;

    float acc[4][4];
#pragma unroll
    for (int i = 0; i < 4; ++i)
#pragma unroll
        for (int j = 0; j < 4; ++j) acc[i][j] = 0.f;

    for (int kc = 0; kc < K; kc += 32) {
#pragma unroll
        for (int rr = 0; rr < 2; ++rr) {
            const int m = mr + rr * 32;
            f32x4 xv = *(const f32x4*)(X + (size_t)(m0 + m) * K + kc + kq * 4);
            f32x4 wv = *(const f32x4*)(Wt + (size_t)(n0 + m) * K + kc + kq * 4);
#pragma unroll
            for (int j = 0; j < 4; ++j) { Xs[kq*4 + j][m] = xv[j]; Ws[kq*4 + j][m] = wv[j]; }
        }
        __syncthreads();
#pragma unroll
        for (int k = 0; k < 32; ++k) {
            f32x4 a = *(const f32x4*)&Xs[k][ty * 4];
            f32x4 b = *(const f32x4*)&Ws[k][tx * 4];
#pragma unroll
            for (int i = 0; i < 4; ++i)
#pragma unroll
                for (int j = 0; j < 4; ++j)
                    acc[i][j] = __builtin_fmaf(a[i], b[j], acc[i][j]);
        }
        __syncthreads();
    }
    f32x4 bv = *(const f32x4*)(bias + n0 + tx * 4);
#pragma unroll
    for (int i = 0; i < 4; ++i) {
        f32x4 o;
#pragma unroll
        for (int j = 0; j < 4; ++j) o[j] = acc[i][j] + bv[j];
        *(f32x4*)(Out + (size_t)(m0 + ty * 4 + i) * N + n0 + tx * 4) = o;
    }
}

// ---------------------------------------------------------------------------
// Recurrent scan, register-only h.  1024 blocks x 64 threads; each wave owns
// 16 cells (cell = cellbase + (lane&15)) for all 512 steps; 1 wave/SIMD.
//
// MFMA 16x16x32 bf16 layouts, lane l, c15=l&15, g4=l>>4:
//   A: lane elems 0-3 hold A[c15][kbase + 4*g4 + e], elems 4-7: +16
//   B: lane elems 0-3 hold B[kbase + 4*g4 + e][c15], elems 4-7: +16
//   D: lane reg e holds D[4*g4 + e][c15]
//
// Tile nt = type*4 + q (type 0..3 = i,f,g,o; q = j-block).  Lane (g4,c15)
// elem e of tile nt = PRE-SCALED gate nt*16+4g4+e of cell c15; scale -log2e
// for i/f/o rows, +2log2e for g rows.  Ext K-slice carries (x*w_ih + bias).
// ---------------------------------------------------------------------------
__global__ __launch_bounds__(64, 1) void lstm_scan(
    const float* __restrict__ x2n,   // [512][16384]
    const float* __restrict__ W_hh,  // [256][64]
    const float* __restrict__ w_ih,  // [256]
    const float* __restrict__ b_ih,  // [256]
    const float* __restrict__ b_hh,  // [256]
    const float* __restrict__ wg,    // [64]
    const float* __restrict__ bg,    // [1]
    float* __restrict__ ON)          // [512][16384]
{
    const int lane = threadIdx.x & 63;
    const int c15 = lane & 15, g4 = lane >> 4;
    const int cellbase = blockIdx.x * 16;
    const float L2E = 1.4426950408889634f;

    // W_hh A-fragments (K=32 pairs) + ext-slice fragments, PRE-SCALED.
    s16x8 afw8[2][16];
    s16x8 afx8[16];
#pragma unroll
    for (int nt = 0; nt < 16; ++nt) {
        const float sc = ((nt >> 2) == 2) ? (2.f * L2E) : (-L2E);
        const float* wrow = W_hh + (size_t)(nt * 16 + c15) * 64;
#pragma unroll
        for (int kp = 0; kp < 2; ++kp) {
            s16x8 v;
#pragma unroll
            for (int half = 0; half < 2; ++half) {
                f32x4 w = *(const f32x4*)(wrow + (kp * 2 + half) * 16 + g4 * 4);
#pragma unroll
                for (int e = 0; e < 4; ++e) v[half * 4 + e] = bf16r(w[e] * sc);
            }
            afw8[kp][nt] = v;
        }
        // Ext slice A row, paired with B-ext (xh, xl, xh, 1 | 1); hi half 0.
        const int g = nt * 16 + c15;
        const float wi = w_ih[g] * sc;
        const float bs = (b_ih[g] + b_hh[g]) * sc;
        const short wh = bf16r(wi);
        const short wl = bf16r(wi - bf2f(wh));
        const short bh_ = bf16r(bs);
        const short bl_ = bf16r(bs - bf2f(bh_));
        s16x8 v = (s16x8){0, 0, 0, 0, 0, 0, 0, 0};
        if (g4 == 0) { v[0] = wh; v[1] = wh; v[2] = wl; v[3] = bh_; }
        else if (g4 == 1) { v[0] = bl_; }
        afx8[nt] = v;
    }

    // wg, laid out to match hv: wg_l[q][e] = wg[q*16 + 4*g4 + e]
    f32x4 wg_l[4];
#pragma unroll
    for (int q = 0; q < 4; ++q) wg_l[q] = *(const f32x4*)(wg + q * 16 + g4 * 4);
    const float bg0 = bg[0];
    const short one_bf = (short)0x3F80;

    f32x4 cst[4];
#pragma unroll
    for (int q = 0; q < 4; ++q) cst[q] = (f32x4){0.f, 0.f, 0.f, 0.f};
    s16x8 bh01 = (s16x8){0, 0, 0, 0, 0, 0, 0, 0};   // h k=0..31  B-fragment
    s16x8 bh23 = (s16x8){0, 0, 0, 0, 0, 0, 0, 0};   // h k=32..63 B-fragment

    float g_s1 = 0.f;      // xor16-reduced g-partial of step t-1
    float g2save = 0.f;    // fully-reduced g of step t-2
    float sp0 = 0.f;

    const size_t cellidx = (size_t)cellbase + c15;
    float xs0 = x2n[cellidx];                        // x(t=0)
    float xs1 = x2n[(size_t)16384 + cellidx];        // x(t=1)

    for (int t = 0; t < 512; ++t) {
        // In-loop pins: make weight fragments loop-carried-modified so the
        // compiler cannot rematerialize them from global each iteration
        // (R6/R9: VGPR_Count 136-184 proved pre-loop pins don't hold).
#pragma unroll
        for (int nt = 0; nt < 16; ++nt) {
            asm volatile("" : "+v"(afw8[0][nt]));
            asm volatile("" : "+v"(afw8[1][nt]));
            asm volatile("" : "+v"(afx8[nt]));
        }

        // finish step t-1's g-reduction (independent of everything below)
        const float s2new = g_s1 + __shfl_xor(g_s1, 32, 64);

        // x for this step; prefetch t+2 (full-step latency margin)
        const float xs_cur = xs0;
        xs0 = xs1;
        xs1 = x2n[(size_t)((t + 2) & 511) * 16384 + cellidx];

        // B extension fragment from x (hi/lo bf16 split), hi half zero
        const short xh = bf16r(xs_cur);
        const short xl = bf16r(xs_cur - bf2f(xh));
        s16x8 bx8 = (s16x8){0, 0, 0, 0, 0, 0, 0, 0};
        if (g4 == 0) { bx8[0] = xh; bx8[1] = xl; bx8[2] = xh; bx8[3] = one_bf; }
        else if (g4 == 1) { bx8[0] = one_bf; }

        // ------ gate-type-major: per q, 12 MFMAs then that q's NL ------
        // (q+1's MFMAs are independent of q's NL -> matrix pipe drains
        //  under the trans/VALU work instead of one serial 840-cyc block)
        unsigned bhw[8];
        float gpart = 0.f;
        const f32x4 zero4 = (f32x4){0.f, 0.f, 0.f, 0.f};
#pragma unroll
        for (int q = 0; q < 4; ++q) {
            f32x4 ai = mfma32(afx8[q], bx8, zero4);
            f32x4 af_ = mfma32(afx8[q + 4], bx8, zero4);
            f32x4 ag_ = mfma32(afx8[q + 8], bx8, zero4);
            f32x4 ao_ = mfma32(afx8[q + 12], bx8, zero4);
            ai  = mfma32(afw8[0][q], bh01, ai);       ai  = mfma32(afw8[1][q], bh23, ai);
            af_ = mfma32(afw8[0][q + 4], bh01, af_);  af_ = mfma32(afw8[1][q + 4], bh23, af_);
            ag_ = mfma32(afw8[0][q + 8], bh01, ag_);  ag_ = mfma32(afw8[1][q + 8], bh23, ag_);
            ao_ = mfma32(afw8[0][q + 12], bh01, ao_); ao_ = mfma32(afw8[1][q + 12], bh23, ao_);

            // NL for this q's 4 elements (e-pairs share the f-rcp)
            f32x4 hv;
#pragma unroll
            for (int ep = 0; ep < 2; ++ep) {
                const int ea = 2 * ep, eb = ea + 1;
                const float ufa = __builtin_amdgcn_exp2f(af_[ea]);
                const float ufb = __builtin_amdgcn_exp2f(af_[eb]);
                const float dfa = 1.f + ufa, dfb = 1.f + ufb;
                const float rf = __builtin_amdgcn_rcpf(dfa * dfb);
                const float sfa = rf * dfb, sfb = rf * dfa;

                const float uia = __builtin_amdgcn_exp2f(ai[ea]);
                const float uib = __builtin_amdgcn_exp2f(ai[eb]);
                const float vga = __builtin_amdgcn_exp2f(ag_[ea]);
                const float vgb = __builtin_amdgcn_exp2f(ag_[eb]);
                const float pa = (vga - 1.f) *
                    __builtin_amdgcn_rcpf((1.f + uia) * (1.f + vga));
                const float pb = (vgb - 1.f) *
                    __builtin_amdgcn_rcpf((1.f + uib) * (1.f + vgb));

                const float ca = __builtin_fmaf(sfa, cst[q][ea], pa);
                const float cb = __builtin_fmaf(sfb, cst[q][eb], pb);
                cst[q][ea] = ca; cst[q][eb] = cb;

                const float uoa = __builtin_amdgcn_exp2f(ao_[ea]);
                const float uob = __builtin_amdgcn_exp2f(ao_[eb]);
                const float vca = __builtin_amdgcn_exp2f(fminf(2.8853900817779268f * ca, 43.f));
                const float vcb = __builtin_amdgcn_exp2f(fminf(2.8853900817779268f * cb, 43.f));
                const float ha = (vca - 1.f) * __builtin_amdgcn_rcpf((1.f + uoa) * (1.f + vca));
                const float hb = (vcb - 1.f) * __builtin_amdgcn_rcpf((1.f + uob) * (1.f + vcb));
                hv[ea] = ha; hv[eb] = hb;
                bhw[q * 2 + ep] = pkbf(ha, hb);     // next-step B-frag word
            }
            gpart = __builtin_fmaf(hv[0], wg_l[q][0], gpart);
            gpart = __builtin_fmaf(hv[1], wg_l[q][1], gpart);
            gpart = __builtin_fmaf(hv[2], wg_l[q][2], gpart);
            gpart = __builtin_fmaf(hv[3], wg_l[q][3], gpart);
        }

        // assemble next-step B fragments (all static indices)
        bh01 = __builtin_bit_cast(s16x8, (u32x4){bhw[0], bhw[1], bhw[2], bhw[3]});
        bh23 = __builtin_bit_cast(s16x8, (u32x4){bhw[4], bhw[5], bhw[6], bhw[7]});

        // out[t,cell] = gain * softplus(x-1); gain = g_t, 1, g_{t-2}
        const float x1 = xs_cur - 1.f;
        const float sp = fmaxf(x1, 0.f) +
            0.6931471805599453f * __builtin_amdgcn_logf(
                1.f + __builtin_amdgcn_exp2f(-1.4426950408889634f * fabsf(x1)));
        if (t >= 2) {
            const float gain = g2save + bg0;         // = g_{t-2}
            if (g4 == 0) {
                ON[(size_t)t * 16384 + cellidx] = gain * sp;
                if (t == 2) ON[cellidx] = gain * sp0;          // gain_0 = g_0
            }
        } else if (t == 1) {
            if (g4 == 0) ON[(size_t)16384 + cellidx] = sp;     // gain = 1
        } else {
            sp0 = sp;                                // ON[0] deferred to t==2
        }
        g2save = s2new;                              // s2 of step t-1
        g_s1 = gpart + __shfl_xor(gpart, 16, 64);    // s1 of step t
    }
}

extern "C" void kernel_launch(void* const* d_in, const int* in_sizes, int n_in,
                              void* d_out, int out_size, void* d_ws, size_t ws_size,
                              hipStream_t stream)
{
    const float* input = (const float*)d_in[0];   // [512][64][128]
    const float* W2n   = (const float*)d_in[1];   // [256][128]
    const float* b2n   = (const float*)d_in[2];   // [256]
    const float* W_ih  = (const float*)d_in[3];   // [256] (4H x 1)
    const float* W_hh  = (const float*)d_in[4];   // [256][64]
    const float* b_ih  = (const float*)d_in[5];   // [256]
    const float* b_hh  = (const float*)d_in[6];   // [256]
    const float* Wg    = (const float*)d_in[7];   // [64]  (1 x H)
    const float* bg    = (const float*)d_in[8];   // [1]
    const float* Wout  = (const float*)d_in[9];   // [64][256]
    const float* bout  = (const float*)d_in[10];  // [64]

    float* x2n = (float*)d_ws;                          // 512*16384 f32 = 32MB
    float* ON  = x2n + (size_t)512 * 16384;             // another 32MB

    // Stage 1: x2n = input @ W2n^T + b2n   (M=32768, N=256, K=128)
    gemm_xwT<<<dim3(512, 4), 256, 0, stream>>>(input, W2n, b2n, x2n, 256, 128);

    // Stage 2: recurrent scan -> ON  (1024 waves = 1/SIMD on all 256 CUs)
    lstm_scan<<<1024, 64, 0, stream>>>(x2n, W_hh, W_ih, b_ih, b_hh, Wg, bg, ON);

    // Stage 3: out = ON @ Wout^T + bout    (M=32768, N=64, K=256)
    gemm_xwT<<<dim3(512, 1), 256, 0, stream>>>(ON, Wout, bout, (float*)d_out, 64, 256);
}